// Round 11
// baseline (44.204 us; speedup 1.0000x reference)
//
#include <hip/hip_runtime.h>
#include <math.h>

constexpr int   NN  = 262144;     // nodes
constexpr int   NE  = 1048576;    // edges
constexpr float DTc = 0.1f;
constexpr float W1 = 1.0f, W2 = 0.5f, W3 = 2.0f, W4 = 0.5f;
constexpr float EPSc = 1e-6f;

constexpr int NB_EDGE = NE / 256;   // 4096 edge blocks
constexpr int NB_NODE = NN / 256;   // 1024 node blocks
constexpr int NB_TOT  = NB_EDGE + NB_NODE;  // 5120, = 1024 groups of (4 edge + 1 node)

typedef float    __attribute__((ext_vector_type(2))) f32x2;
typedef float    __attribute__((ext_vector_type(4))) f32x4;
typedef float    __attribute__((ext_vector_type(4), aligned(4))) f32x4u;
typedef float    __attribute__((ext_vector_type(2), aligned(4))) f32x2u;
typedef int      __attribute__((ext_vector_type(2))) i32x2;
typedef _Float16 __attribute__((ext_vector_type(8))) f16x8;               // 16B pose record

struct V3 { float x, y, z; };
struct Q4 { float x, y, z, w; };

__device__ __forceinline__ V3 v3(float x, float y, float z) { V3 r{x, y, z}; return r; }
__device__ __forceinline__ V3 vadd(V3 a, V3 b) { return v3(a.x + b.x, a.y + b.y, a.z + b.z); }
__device__ __forceinline__ V3 vsub(V3 a, V3 b) { return v3(a.x - b.x, a.y - b.y, a.z - b.z); }
__device__ __forceinline__ V3 vscale(float s, V3 a) { return v3(s * a.x, s * a.y, s * a.z); }
__device__ __forceinline__ V3 vcross(V3 a, V3 b) {
    return v3(a.y * b.z - a.z * b.y, a.z * b.x - a.x * b.z, a.x * b.y - a.y * b.x);
}
__device__ __forceinline__ float vdot(V3 a, V3 b) { return a.x * b.x + a.y * b.y + a.z * b.z; }

__device__ __forceinline__ Q4 qmul(Q4 a, Q4 b) {
    Q4 r;
    r.w = a.w * b.w - (a.x * b.x + a.y * b.y + a.z * b.z);
    r.x = a.w * b.x + b.w * a.x + (a.y * b.z - a.z * b.y);
    r.y = a.w * b.y + b.w * a.y + (a.z * b.x - a.x * b.z);
    r.z = a.w * b.z + b.w * a.z + (a.x * b.y - a.y * b.x);
    return r;
}
__device__ __forceinline__ Q4 qconj(Q4 q) { Q4 r{-q.x, -q.y, -q.z, q.w}; return r; }
__device__ __forceinline__ V3 qrot(Q4 q, V3 x) {
    V3 v = v3(q.x, q.y, q.z);
    V3 c1 = vadd(vcross(v, x), vscale(q.w, x));
    return vadd(x, vscale(2.0f, vcross(v, c1)));
}
__device__ __forceinline__ V3 so3_log(Q4 q) {
    V3 v = v3(q.x, q.y, q.z);
    float n = sqrtf(vdot(v, v));
    float theta = 2.0f * atan2f(n, q.w);
    float factor;
    if (n < EPSc) {
        float w_safe = (fabsf(q.w) < EPSc) ? 1.0f : q.w;
        factor = 2.0f / w_safe;
    } else {
        factor = theta / n;
    }
    return vscale(factor, v);
}

struct TP { V3 tau; V3 phi; };

// qrot linear in x: -qrot(q,a)+qrot(q,b) == qrot(q, b-a) -> 2 qrots total.
__device__ __forceinline__ TP edge_residual(V3 tm, Q4 qm, V3 t1, Q4 q1,
                                            V3 t2, Q4 q2) {
    Q4 qa = qconj(q1);
    V3 tb = qrot(qa, vsub(t2, t1));
    Q4 qb = qmul(qa, q2);
    Q4 qc = qconj(qm);
    V3 te = qrot(qc, vsub(tb, tm));
    Q4 qe = qmul(qc, qb);

    V3 phi = so3_log(qe);
    float th = sqrtf(vdot(phi, phi));
    float coef;
    if (th < EPSc) {
        coef = 1.0f / 12.0f + th * th / 720.0f;
    } else {
        float s, c;
        sincosf(th, &s, &c);
        coef = 1.0f / (th * th) - (1.0f + c) / (2.0f * th * s);
    }
    V3 pxt = vcross(phi, te);
    V3 tau = vadd(vsub(te, vscale(0.5f, pxt)), vscale(coef, vcross(phi, pxt)));
    TP r; r.tau = tau; r.phi = phi; return r;
}

// K1: pack-only fp16 table build (11MB traffic, ~2us).
__global__ __launch_bounds__(256) void pack_kernel(const float* __restrict__ pose,
                                                   f16x8* __restrict__ ppH) {
    int i = blockIdx.x * blockDim.x + threadIdx.x;
    if (i >= NN) return;
    f32x4u a = *(const f32x4u*)(pose + 7 * (size_t)i);
    f32x4u b = *(const f32x4u*)(pose + 7 * (size_t)i + 3);
    f16x8 rec = {(_Float16)a.x, (_Float16)a.y, (_Float16)a.z,
                 (_Float16)b.x, (_Float16)b.y, (_Float16)b.z,
                 (_Float16)b.w, (_Float16)0.0f};
    ppH[i] = rec;
}

// K2: FUSED edge+node kernel. Blocks interleaved 4 edge : 1 node so each
// resident cohort mixes gather-latency-bound edge waves (idle BW) with
// stream-BW-bound node waves (fills the idle BW).
__global__ __launch_bounds__(256) void fused_kernel(
    const float* __restrict__ pose, const float* __restrict__ vel,
    const float* __restrict__ vmot, const float* __restrict__ imu_drot,
    const float* __restrict__ body_dvel, const float* __restrict__ body_dpos,
    const int* __restrict__ vlink, const f16x8* __restrict__ ppH,
    float* __restrict__ out)
{
    int b = blockIdx.x;
    int g = b / 5, rdx = b - 5 * g;
    if (rdx < 4) {
        // ---------------- edge block: eb in [0,4096) ----------------
        int eb = g * 4 + rdx;
        int e  = eb * 256 + threadIdx.x;
        i32x2 l = __builtin_nontemporal_load((const i32x2*)vlink + e);
        const float* pm = vmot + 7 * (size_t)e;
        f32x4u ma = __builtin_nontemporal_load((const f32x4u*)(pm));      // t0 t1 t2 q0
        f32x4u mb = __builtin_nontemporal_load((const f32x4u*)(pm + 3));  // q0 q1 q2 q3
        f16x8 g1 = ppH[l.x];   // allocating 16B gathers (L2-resident table)
        f16x8 g2 = ppH[l.y];

        TP r = edge_residual(
            v3(ma.x, ma.y, ma.z), Q4{mb.x, mb.y, mb.z, mb.w},
            v3((float)g1[0], (float)g1[1], (float)g1[2]),
            Q4{(float)g1[3], (float)g1[4], (float)g1[5], (float)g1[6]},
            v3((float)g2[0], (float)g2[1], (float)g2[2]),
            Q4{(float)g2[3], (float)g2[4], (float)g2[5], (float)g2[6]});

        f32x2* o2 = (f32x2*)(out + 6 * (size_t)e);   // 24B stride, 8B-aligned
        f32x2 a = {W1 * r.tau.x, W1 * r.tau.y};
        f32x2 bb = {W1 * r.tau.z, W1 * r.phi.x};
        f32x2 c = {W1 * r.phi.y, W1 * r.phi.z};
        __builtin_nontemporal_store(a, o2);
        __builtin_nontemporal_store(bb, o2 + 1);
        __builtin_nontemporal_store(c, o2 + 2);
    } else {
        // ---------------- node block: nb = g in [0,1024) ----------------
        int i = g * 256 + threadIdx.x;
        if (i >= NN - 1) return;
        f32x4u pa0 = __builtin_nontemporal_load((const f32x4u*)(pose + 7 * (size_t)i));
        f32x4u pa1 = __builtin_nontemporal_load((const f32x4u*)(pose + 7 * (size_t)i + 3));
        V3 tr1 = v3(pa0.x, pa0.y, pa0.z); Q4 r1 = {pa1.x, pa1.y, pa1.z, pa1.w};
        f32x4u pb0 = __builtin_nontemporal_load((const f32x4u*)(pose + 7 * (size_t)(i + 1)));
        f32x4u pb1 = __builtin_nontemporal_load((const f32x4u*)(pose + 7 * (size_t)(i + 1) + 3));
        V3 tr2 = v3(pb0.x, pb0.y, pb0.z); Q4 r2 = {pb1.x, pb1.y, pb1.z, pb1.w};

        f32x4u vv = __builtin_nontemporal_load((const f32x4u*)(vel + 3 * (size_t)i));
        f32x2u vw = __builtin_nontemporal_load((const f32x2u*)(vel + 3 * (size_t)i + 4));
        V3 v1 = v3(vv.x, vv.y, vv.z);
        V3 v2 = v3(vv.w, vw.x, vw.y);
        f32x2u bv0 = __builtin_nontemporal_load((const f32x2u*)(body_dvel + 3 * (size_t)i));
        float  bv2 = __builtin_nontemporal_load(body_dvel + 3 * (size_t)i + 2);
        f32x2u bp0 = __builtin_nontemporal_load((const f32x2u*)(body_dpos + 3 * (size_t)i));
        float  bp2 = __builtin_nontemporal_load(body_dpos + 3 * (size_t)i + 2);
        V3 bdv = v3(bv0.x, bv0.y, bv2);
        V3 bdp = v3(bp0.x, bp0.y, bp2);
        f32x4 id4 = __builtin_nontemporal_load((const f32x4*)(imu_drot + 4 * (size_t)i));
        Q4 idr = {id4.x, id4.y, id4.z, id4.w};

        V3 imu_dvel = qrot(r1, bdv);
        V3 adjvel = vsub(imu_dvel, vsub(v2, v1));
        Q4 qrel = qmul(idr, qmul(qconj(r1), r2));
        V3 imurot = so3_log(qrel);
        V3 imu_dpos = vadd(qrot(r1, bdp), vscale(DTc, v1));
        V3 transvel = vsub(imu_dpos, vsub(tr2, tr1));

        size_t base = (size_t)6 * NE;
        size_t nm1 = (size_t)(NN - 1);
        float* oa = out + base + 3 * (size_t)i;
        __builtin_nontemporal_store(W2 * adjvel.x, oa);
        __builtin_nontemporal_store(W2 * adjvel.y, oa + 1);
        __builtin_nontemporal_store(W2 * adjvel.z, oa + 2);
        float* ob = out + base + 3 * nm1 + 3 * (size_t)i;
        __builtin_nontemporal_store(W3 * imurot.x, ob);
        __builtin_nontemporal_store(W3 * imurot.y, ob + 1);
        __builtin_nontemporal_store(W3 * imurot.z, ob + 2);
        float* oc = out + base + 6 * nm1 + 3 * (size_t)i;
        __builtin_nontemporal_store(W4 * transvel.x, oc);
        __builtin_nontemporal_store(W4 * transvel.y, oc + 1);
        __builtin_nontemporal_store(W4 * transvel.z, oc + 2);
    }
}

// Fallback (no workspace): 1 edge/thread, raw f32 pose gathers, pure HIP.
__global__ __launch_bounds__(256) void vigraph_fallback(
    const float* __restrict__ pose, const float* __restrict__ vel,
    const float* __restrict__ vmot, const float* __restrict__ imu_drot,
    const float* __restrict__ body_dvel, const float* __restrict__ body_dpos,
    const int* __restrict__ vlink, float* __restrict__ out)
{
    int tid = blockIdx.x * blockDim.x + threadIdx.x;
    if (tid < NE) {
        int e = tid;
        const float* pm = vmot + 7 * (size_t)e;
        int i1 = vlink[2 * (size_t)e];
        int i2 = vlink[2 * (size_t)e + 1];
        const float* p1 = pose + 7 * (size_t)i1;
        const float* p2 = pose + 7 * (size_t)i2;
        TP r = edge_residual(v3(pm[0], pm[1], pm[2]), Q4{pm[3], pm[4], pm[5], pm[6]},
                             v3(p1[0], p1[1], p1[2]), Q4{p1[3], p1[4], p1[5], p1[6]},
                             v3(p2[0], p2[1], p2[2]), Q4{p2[3], p2[4], p2[5], p2[6]});
        float* o = out + 6 * (size_t)e;
        o[0] = W1 * r.tau.x; o[1] = W1 * r.tau.y; o[2] = W1 * r.tau.z;
        o[3] = W1 * r.phi.x; o[4] = W1 * r.phi.y; o[5] = W1 * r.phi.z;
    } else {
        int i = tid - NE;
        if (i >= NN - 1) return;
        const float* pa = pose + 7 * (size_t)i;
        const float* pb = pose + 7 * (size_t)(i + 1);
        V3 tr1 = v3(pa[0], pa[1], pa[2]); Q4 r1 = {pa[3], pa[4], pa[5], pa[6]};
        V3 tr2 = v3(pb[0], pb[1], pb[2]); Q4 r2 = {pb[3], pb[4], pb[5], pb[6]};
        V3 v1 = v3(vel[3 * (size_t)i], vel[3 * (size_t)i + 1], vel[3 * (size_t)i + 2]);
        V3 v2 = v3(vel[3 * (size_t)(i + 1)], vel[3 * (size_t)(i + 1) + 1], vel[3 * (size_t)(i + 1) + 2]);
        V3 bdv = v3(body_dvel[3 * (size_t)i], body_dvel[3 * (size_t)i + 1], body_dvel[3 * (size_t)i + 2]);
        V3 bdp = v3(body_dpos[3 * (size_t)i], body_dpos[3 * (size_t)i + 1], body_dpos[3 * (size_t)i + 2]);
        Q4 idr = {imu_drot[4 * (size_t)i], imu_drot[4 * (size_t)i + 1],
                  imu_drot[4 * (size_t)i + 2], imu_drot[4 * (size_t)i + 3]};
        V3 imu_dvel = qrot(r1, bdv);
        V3 adjvel = vsub(imu_dvel, vsub(v2, v1));
        Q4 qrel = qmul(idr, qmul(qconj(r1), r2));
        V3 imurot = so3_log(qrel);
        V3 imu_dpos = vadd(qrot(r1, bdp), vscale(DTc, v1));
        V3 transvel = vsub(imu_dpos, vsub(tr2, tr1));
        size_t base = (size_t)6 * NE;
        size_t nm1 = (size_t)(NN - 1);
        float* oa = out + base + 3 * (size_t)i;
        oa[0] = W2 * adjvel.x; oa[1] = W2 * adjvel.y; oa[2] = W2 * adjvel.z;
        float* ob = out + base + 3 * nm1 + 3 * (size_t)i;
        ob[0] = W3 * imurot.x; ob[1] = W3 * imurot.y; ob[2] = W3 * imurot.z;
        float* oc = out + base + 6 * nm1 + 3 * (size_t)i;
        oc[0] = W4 * transvel.x; oc[1] = W4 * transvel.y; oc[2] = W4 * transvel.z;
    }
}

extern "C" void kernel_launch(void* const* d_in, const int* in_sizes, int n_in,
                              void* d_out, int out_size, void* d_ws, size_t ws_size,
                              hipStream_t stream) {
    const float* pose      = (const float*)d_in[0];
    const float* vel       = (const float*)d_in[1];
    const float* vmot      = (const float*)d_in[2];
    const float* imu_drot  = (const float*)d_in[3];
    const float* body_dvel = (const float*)d_in[4];
    const float* body_dpos = (const float*)d_in[5];
    const int*   vlink     = (const int*)d_in[6];
    float* out = (float*)d_out;

    const size_t table_bytes = (size_t)NN * 16;
    if (ws_size >= table_bytes) {
        f16x8* ppH = (f16x8*)d_ws;
        pack_kernel<<<NB_NODE, 256, 0, stream>>>(pose, ppH);
        fused_kernel<<<NB_TOT, 256, 0, stream>>>(pose, vel, vmot, imu_drot,
                                                 body_dvel, body_dpos, vlink, ppH, out);
    } else {
        int total = NE + (NN - 1);
        int grid = (total + 255) / 256;
        vigraph_fallback<<<grid, 256, 0, stream>>>(pose, vel, vmot, imu_drot,
                                                   body_dvel, body_dpos, vlink, out);
    }
}

// Round 12
// 39.661 us; speedup vs baseline: 1.1145x; 1.1145x over previous
//
#include <hip/hip_runtime.h>
#include <math.h>

constexpr int   NN  = 262144;     // nodes
constexpr int   NE  = 1048576;    // edges
constexpr float DTc = 0.1f;
constexpr float W1 = 1.0f, W2 = 0.5f, W3 = 2.0f, W4 = 0.5f;
constexpr float EPSc = 1e-6f;

typedef float    __attribute__((ext_vector_type(2))) f32x2;
typedef float    __attribute__((ext_vector_type(4))) f32x4;
typedef float    __attribute__((ext_vector_type(4), aligned(4))) f32x4u;  // 4B-aligned vec load
typedef float    __attribute__((ext_vector_type(2), aligned(4))) f32x2u;
typedef int      __attribute__((ext_vector_type(2))) i32x2;
typedef _Float16 __attribute__((ext_vector_type(8))) f16x8;               // 16B pose record

struct V3 { float x, y, z; };
struct Q4 { float x, y, z, w; };

__device__ __forceinline__ V3 v3(float x, float y, float z) { V3 r{x, y, z}; return r; }
__device__ __forceinline__ V3 vadd(V3 a, V3 b) { return v3(a.x + b.x, a.y + b.y, a.z + b.z); }
__device__ __forceinline__ V3 vsub(V3 a, V3 b) { return v3(a.x - b.x, a.y - b.y, a.z - b.z); }
__device__ __forceinline__ V3 vscale(float s, V3 a) { return v3(s * a.x, s * a.y, s * a.z); }
__device__ __forceinline__ V3 vcross(V3 a, V3 b) {
    return v3(a.y * b.z - a.z * b.y, a.z * b.x - a.x * b.z, a.x * b.y - a.y * b.x);
}
__device__ __forceinline__ float vdot(V3 a, V3 b) { return a.x * b.x + a.y * b.y + a.z * b.z; }

__device__ __forceinline__ Q4 qmul(Q4 a, Q4 b) {
    Q4 r;
    r.w = a.w * b.w - (a.x * b.x + a.y * b.y + a.z * b.z);
    r.x = a.w * b.x + b.w * a.x + (a.y * b.z - a.z * b.y);
    r.y = a.w * b.y + b.w * a.y + (a.z * b.x - a.x * b.z);
    r.z = a.w * b.z + b.w * a.z + (a.x * b.y - a.y * b.x);
    return r;
}
__device__ __forceinline__ Q4 qconj(Q4 q) { Q4 r{-q.x, -q.y, -q.z, q.w}; return r; }
__device__ __forceinline__ V3 qrot(Q4 q, V3 x) {
    V3 v = v3(q.x, q.y, q.z);
    V3 c1 = vadd(vcross(v, x), vscale(q.w, x));
    return vadd(x, vscale(2.0f, vcross(v, c1)));
}
__device__ __forceinline__ V3 so3_log(Q4 q) {
    V3 v = v3(q.x, q.y, q.z);
    float n = sqrtf(vdot(v, v));
    float theta = 2.0f * atan2f(n, q.w);
    float factor;
    if (n < EPSc) {
        float w_safe = (fabsf(q.w) < EPSc) ? 1.0f : q.w;
        factor = 2.0f / w_safe;
    } else {
        factor = theta / n;
    }
    return vscale(factor, v);
}

__device__ __forceinline__ void edge_residual(V3 tm, Q4 qm, V3 t1, Q4 q1,
                                              V3 t2, Q4 q2, float* __restrict__ o) {
    // A = se3_inv(pose1)
    Q4 qa = qconj(q1);
    V3 ta = vscale(-1.0f, qrot(qa, t1));
    // B = A * pose2
    V3 tb = vadd(ta, qrot(qa, t2));
    Q4 qb = qmul(qa, q2);
    // C = se3_inv(vmot)
    Q4 qc = qconj(qm);
    V3 tc = vscale(-1.0f, qrot(qc, tm));
    // err = C * B
    V3 te = vadd(tc, qrot(qc, tb));
    Q4 qe = qmul(qc, qb);

    V3 phi = so3_log(qe);
    float th = sqrtf(vdot(phi, phi));
    float coef;
    if (th < EPSc) {
        coef = 1.0f / 12.0f + th * th / 720.0f;
    } else {
        float s, c;
        sincosf(th, &s, &c);
        coef = 1.0f / (th * th) - (1.0f + c) / (2.0f * th * s);
    }
    V3 pxt = vcross(phi, te);
    V3 tau = vadd(vsub(te, vscale(0.5f, pxt)), vscale(coef, vcross(phi, pxt)));

    f32x2* o2 = (f32x2*)o;  // 24B record stride -> 8B aligned
    f32x2 a = {W1 * tau.x, W1 * tau.y};
    f32x2 b = {W1 * tau.z, W1 * phi.x};
    f32x2 c = {W1 * phi.y, W1 * phi.z};
    __builtin_nontemporal_store(a, o2);
    __builtin_nontemporal_store(b, o2 + 1);
    __builtin_nontemporal_store(c, o2 + 2);
}

// Kernel 1: node residuals + build fp16 pose table (16B records, 4MB total).
// Record: [tx ty tz qx qy qz qw 0] as 8 halves.
__global__ __launch_bounds__(256) void node_pack_kernel(
    const float* __restrict__ pose, const float* __restrict__ vel,
    const float* __restrict__ imu_drot, const float* __restrict__ body_dvel,
    const float* __restrict__ body_dpos, f16x8* __restrict__ ppH,
    float* __restrict__ out)
{
    int i = blockIdx.x * blockDim.x + threadIdx.x;
    if (i >= NN) return;
    // pose i: two overlapping 16B loads over the 28B record (4B-aligned OK)
    f32x4u pa0 = *(const f32x4u*)(pose + 7 * (size_t)i);      // tx ty tz qx
    f32x4u pa1 = *(const f32x4u*)(pose + 7 * (size_t)i + 3);  // qx qy qz qw
    f16x8 rec = {(_Float16)pa0.x, (_Float16)pa0.y, (_Float16)pa0.z,
                 (_Float16)pa1.x, (_Float16)pa1.y, (_Float16)pa1.z,
                 (_Float16)pa1.w, (_Float16)0.0f};
    ppH[i] = rec;
    if (i >= NN - 1) return;

    V3 tr1 = v3(pa0.x, pa0.y, pa0.z); Q4 r1 = {pa1.x, pa1.y, pa1.z, pa1.w};
    f32x4u pb0 = *(const f32x4u*)(pose + 7 * (size_t)(i + 1));
    f32x4u pb1 = *(const f32x4u*)(pose + 7 * (size_t)(i + 1) + 3);
    V3 tr2 = v3(pb0.x, pb0.y, pb0.z); Q4 r2 = {pb1.x, pb1.y, pb1.z, pb1.w};

    f32x4u vv = *(const f32x4u*)(vel + 3 * (size_t)i);        // v1x v1y v1z v2x
    f32x2u vw = *(const f32x2u*)(vel + 3 * (size_t)i + 4);    // v2y v2z
    V3 v1 = v3(vv.x, vv.y, vv.z);
    V3 v2 = v3(vv.w, vw.x, vw.y);
    V3 bdv = v3(body_dvel[3 * (size_t)i], body_dvel[3 * (size_t)i + 1], body_dvel[3 * (size_t)i + 2]);
    V3 bdp = v3(body_dpos[3 * (size_t)i], body_dpos[3 * (size_t)i + 1], body_dpos[3 * (size_t)i + 2]);
    f32x4 id4 = *(const f32x4*)(imu_drot + 4 * (size_t)i);    // 16B aligned
    Q4 idr = {id4.x, id4.y, id4.z, id4.w};

    V3 imu_dvel = qrot(r1, bdv);
    V3 adjvel = vsub(imu_dvel, vsub(v2, v1));
    Q4 qrel = qmul(idr, qmul(qconj(r1), r2));
    V3 imurot = so3_log(qrel);
    V3 imu_dpos = vadd(qrot(r1, bdp), vscale(DTc, v1));
    V3 transvel = vsub(imu_dpos, vsub(tr2, tr1));

    size_t base = (size_t)6 * NE;
    size_t nm1 = (size_t)(NN - 1);
    float* oa = out + base + 3 * (size_t)i;
    oa[0] = W2 * adjvel.x; oa[1] = W2 * adjvel.y; oa[2] = W2 * adjvel.z;
    float* ob = out + base + 3 * nm1 + 3 * (size_t)i;
    ob[0] = W3 * imurot.x; ob[1] = W3 * imurot.y; ob[2] = W3 * imurot.z;
    float* oc = out + base + 6 * nm1 + 3 * (size_t)i;
    oc[0] = W4 * transvel.x; oc[1] = W4 * transvel.y; oc[2] = W4 * transvel.z;
}

// Kernel 2: edge residuals. vmot LDS-staged coalesced (nt loads); pose via
// one 16B fp16 gather per endpoint (4MB L2-resident table).
__global__ __launch_bounds__(256) void edge_kernel(
    const float* __restrict__ vmot, const int* __restrict__ vlink,
    const f16x8* __restrict__ ppH, float* __restrict__ out)
{
    __shared__ float smv[256 * 7];
    int e0 = blockIdx.x * 256;
    // cooperative coalesced stage of 256 edges' vmot (7168B = 448 float4)
    const f32x4* src = (const f32x4*)(vmot + (size_t)e0 * 7);
    {
        int idx = threadIdx.x;
        ((f32x4*)smv)[idx] = __builtin_nontemporal_load(src + idx);
        idx += 256;
        if (idx < 448) ((f32x4*)smv)[idx] = __builtin_nontemporal_load(src + idx);
    }
    int e = e0 + threadIdx.x;
    i32x2 l = __builtin_nontemporal_load((const i32x2*)vlink + e);
    f16x8 g1 = ppH[l.x];   // one 16B gather per endpoint
    f16x8 g2 = ppH[l.y];
    __syncthreads();
    float m[7];
#pragma unroll
    for (int k = 0; k < 7; ++k) m[k] = smv[7 * threadIdx.x + k];

    V3 t1 = v3((float)g1[0], (float)g1[1], (float)g1[2]);
    Q4 q1 = {(float)g1[3], (float)g1[4], (float)g1[5], (float)g1[6]};
    V3 t2 = v3((float)g2[0], (float)g2[1], (float)g2[2]);
    Q4 q2 = {(float)g2[3], (float)g2[4], (float)g2[5], (float)g2[6]};

    edge_residual(v3(m[0], m[1], m[2]), Q4{m[3], m[4], m[5], m[6]},
                  t1, q1, t2, q2, out + 6 * (size_t)e);
}

// Fallback (no workspace): 1 edge/thread, raw f32 pose gathers.
__global__ __launch_bounds__(256) void vigraph_fallback(
    const float* __restrict__ pose, const float* __restrict__ vel,
    const float* __restrict__ vmot, const float* __restrict__ imu_drot,
    const float* __restrict__ body_dvel, const float* __restrict__ body_dpos,
    const int* __restrict__ vlink, float* __restrict__ out)
{
    int tid = blockIdx.x * blockDim.x + threadIdx.x;
    if (tid < NE) {
        int e = tid;
        const float* pm = vmot + 7 * (size_t)e;
        int i1 = vlink[2 * (size_t)e];
        int i2 = vlink[2 * (size_t)e + 1];
        const float* p1 = pose + 7 * (size_t)i1;
        const float* p2 = pose + 7 * (size_t)i2;
        edge_residual(v3(pm[0], pm[1], pm[2]), Q4{pm[3], pm[4], pm[5], pm[6]},
                      v3(p1[0], p1[1], p1[2]), Q4{p1[3], p1[4], p1[5], p1[6]},
                      v3(p2[0], p2[1], p2[2]), Q4{p2[3], p2[4], p2[5], p2[6]},
                      out + 6 * (size_t)e);
    } else {
        int i = tid - NE;
        if (i >= NN - 1) return;
        const float* pa = pose + 7 * (size_t)i;
        const float* pb = pose + 7 * (size_t)(i + 1);
        V3 tr1 = v3(pa[0], pa[1], pa[2]); Q4 r1 = {pa[3], pa[4], pa[5], pa[6]};
        V3 tr2 = v3(pb[0], pb[1], pb[2]); Q4 r2 = {pb[3], pb[4], pb[5], pb[6]};
        V3 v1 = v3(vel[3 * (size_t)i], vel[3 * (size_t)i + 1], vel[3 * (size_t)i + 2]);
        V3 v2 = v3(vel[3 * (size_t)(i + 1)], vel[3 * (size_t)(i + 1) + 1], vel[3 * (size_t)(i + 1) + 2]);
        V3 bdv = v3(body_dvel[3 * (size_t)i], body_dvel[3 * (size_t)i + 1], body_dvel[3 * (size_t)i + 2]);
        V3 bdp = v3(body_dpos[3 * (size_t)i], body_dpos[3 * (size_t)i + 1], body_dpos[3 * (size_t)i + 2]);
        Q4 idr = {imu_drot[4 * (size_t)i], imu_drot[4 * (size_t)i + 1],
                  imu_drot[4 * (size_t)i + 2], imu_drot[4 * (size_t)i + 3]};
        V3 imu_dvel = qrot(r1, bdv);
        V3 adjvel = vsub(imu_dvel, vsub(v2, v1));
        Q4 qrel = qmul(idr, qmul(qconj(r1), r2));
        V3 imurot = so3_log(qrel);
        V3 imu_dpos = vadd(qrot(r1, bdp), vscale(DTc, v1));
        V3 transvel = vsub(imu_dpos, vsub(tr2, tr1));
        size_t base = (size_t)6 * NE;
        size_t nm1 = (size_t)(NN - 1);
        float* oa = out + base + 3 * (size_t)i;
        oa[0] = W2 * adjvel.x; oa[1] = W2 * adjvel.y; oa[2] = W2 * adjvel.z;
        float* ob = out + base + 3 * nm1 + 3 * (size_t)i;
        ob[0] = W3 * imurot.x; ob[1] = W3 * imurot.y; ob[2] = W3 * imurot.z;
        float* oc = out + base + 6 * nm1 + 3 * (size_t)i;
        oc[0] = W4 * transvel.x; oc[1] = W4 * transvel.y; oc[2] = W4 * transvel.z;
    }
}

extern "C" void kernel_launch(void* const* d_in, const int* in_sizes, int n_in,
                              void* d_out, int out_size, void* d_ws, size_t ws_size,
                              hipStream_t stream) {
    const float* pose      = (const float*)d_in[0];
    const float* vel       = (const float*)d_in[1];
    const float* vmot      = (const float*)d_in[2];
    const float* imu_drot  = (const float*)d_in[3];
    const float* body_dvel = (const float*)d_in[4];
    const float* body_dpos = (const float*)d_in[5];
    const int*   vlink     = (const int*)d_in[6];
    float* out = (float*)d_out;

    const size_t table_bytes = (size_t)NN * 16;
    if (ws_size >= table_bytes) {
        f16x8* ppH = (f16x8*)d_ws;
        node_pack_kernel<<<NN / 256, 256, 0, stream>>>(pose, vel, imu_drot,
                                                       body_dvel, body_dpos, ppH, out);
        edge_kernel<<<NE / 256, 256, 0, stream>>>(vmot, vlink, ppH, out);
    } else {
        int total = NE + (NN - 1);
        int grid = (total + 255) / 256;
        vigraph_fallback<<<grid, 256, 0, stream>>>(pose, vel, vmot, imu_drot,
                                                   body_dvel, body_dpos, vlink, out);
    }
}